// Round 6
// baseline (100.783 us; speedup 1.0000x reference)
//
#include <hip/hip_runtime.h>
#include <hip/hip_bf16.h>
#include <math.h>

#define NPIX 4096
#define CH 64
#define BATCH 4
#define NSPLIT 4

typedef __attribute__((ext_vector_type(8))) short short8;
typedef __attribute__((ext_vector_type(4))) float f32x4;
typedef __attribute__((ext_vector_type(4))) unsigned short us4;
typedef __attribute__((ext_vector_type(4))) unsigned int u32x4;

static __device__ __forceinline__ unsigned short f2bf(float f) {
  union { float f; unsigned u; } v; v.f = f;
  unsigned u = v.u;
  unsigned r = u + 0x7FFF + ((u >> 16) & 1);
  return (unsigned short)(r >> 16);
}

static __device__ __forceinline__ unsigned cvtpk(float lo, float hi) {
  unsigned r;
  asm("v_cvt_pk_bf16_f32 %0, %1, %2" : "=v"(r) : "v"(lo), "v"(hi));
  return r;
}

// ---------------- K_ln: LayerNorm over C; out f32 spatial (opt) + bf16 pixmajor
template<bool F32OUT>
__global__ __launch_bounds__(256) void k_ln(
    const float* __restrict__ x, const float* __restrict__ lg, const float* __restrict__ lb,
    float* __restrict__ xn, unsigned short* __restrict__ xnT)
{
  __shared__ float xT[64][64];                  // [c][px]
  int tid = threadIdx.x, px = tid & 63, g = tid >> 6;
  int idx = blockIdx.x * 64 + px;
  int b = idx >> 12, p = idx & 4095;
  const float* xb = x + (size_t)b * CH * NPIX + p;
  for (int j = 0; j < 16; ++j) { int c = 16 * g + j; xT[c][px] = xb[(size_t)c * NPIX]; }
  __syncthreads();
  float xv[64]; float s = 0.f;
#pragma unroll
  for (int c = 0; c < 64; ++c) { xv[c] = xT[c][px]; s += xv[c]; }
  float mu = s * (1.f / 64.f), vs = 0.f;
#pragma unroll
  for (int c = 0; c < 64; ++c) { float d = xv[c] - mu; vs += d * d; }
  float rs = rsqrtf(vs * (1.f / 64.f) + 1e-5f);
#pragma unroll
  for (int c = 0; c < 64; ++c) xv[c] = (xv[c] - mu) * rs * lg[c] + lb[c];

  float* xnb = F32OUT ? (xn + (size_t)b * CH * NPIX + p) : nullptr;
  unsigned short* tp = xnT + (size_t)idx * 64;
#define LN_WR(C0)                                                              \
  {                                                                            \
    unsigned short t[16];                                                      \
    _Pragma("unroll") for (int j = 0; j < 16; ++j) {                           \
      float v = xv[C0 + j];                                                    \
      if (F32OUT) xnb[(size_t)(C0 + j) * NPIX] = v;                            \
      t[j] = f2bf(v);                                                          \
    }                                                                          \
    *(short8*)(tp + C0) = *(short8*)t;                                         \
    *(short8*)(tp + C0 + 8) = *(short8*)(t + 8);                               \
  }
  if (g == 0) LN_WR(0)
  else if (g == 1) LN_WR(16)
  else if (g == 2) LN_WR(32)
  else LN_WR(48)
#undef LN_WR
}

// ---------------- K_gemm: out[o][p] = sum_c W[o][c] * InT[p][c]  (+bias)
template<int OC, int IC, bool RES, bool BF16OUT>
__global__ __launch_bounds__(256) void k_gemm(
    const float* __restrict__ W, const float* __restrict__ bias,
    const unsigned short* __restrict__ InT, const float* __restrict__ res,
    float scale, float* __restrict__ outF, unsigned short* __restrict__ outB)
{
  constexpr int OT = OC / 64;
  constexpr int KC = IC / 32;
  int tid = threadIdx.x;
  int wid = tid >> 6, lane = tid & 63;
  int l15 = lane & 15, g = lane >> 4;
  int b = blockIdx.y;
  int pxb = blockIdx.x * 64;
  const unsigned short* In = InT + ((size_t)b * NPIX + pxb) * IC;

  short8 af[OT][KC];
#pragma unroll
  for (int ot = 0; ot < OT; ++ot)
#pragma unroll
    for (int kc = 0; kc < KC; ++kc) {
      int o = wid * 16 * OT + ot * 16 + l15;
      const float* wp = W + (size_t)o * IC + kc * 32 + 8 * g;
      unsigned short t[8];
#pragma unroll
      for (int j = 0; j < 8; ++j) t[j] = f2bf(wp[j]);
      af[ot][kc] = *(short8*)t;
    }

  float bv[OT][4];
#pragma unroll
  for (int ot = 0; ot < OT; ++ot)
#pragma unroll
    for (int r = 0; r < 4; ++r)
      bv[ot][r] = bias[wid * 16 * OT + ot * 16 + 4 * g + r];

  f32x4 acc[OT][4];
#pragma unroll
  for (int ot = 0; ot < OT; ++ot)
#pragma unroll
    for (int ct = 0; ct < 4; ++ct)
      acc[ot][ct] = (f32x4){bv[ot][0], bv[ot][1], bv[ot][2], bv[ot][3]};

#pragma unroll
  for (int ct = 0; ct < 4; ++ct) {
    short8 bf[KC];
#pragma unroll
    for (int kc = 0; kc < KC; ++kc)
      bf[kc] = *(const short8*)(In + (size_t)(ct * 16 + l15) * IC + kc * 32 + 8 * g);
#pragma unroll
    for (int ot = 0; ot < OT; ++ot)
#pragma unroll
      for (int kc = 0; kc < KC; ++kc)
        acc[ot][ct] = __builtin_amdgcn_mfma_f32_16x16x32_bf16(af[ot][kc], bf[kc], acc[ot][ct], 0, 0, 0);
  }

#pragma unroll
  for (int ot = 0; ot < OT; ++ot)
#pragma unroll
    for (int ct = 0; ct < 4; ++ct) {
      int p = pxb + ct * 16 + l15;
      if constexpr (BF16OUT) {
        us4 v;
#pragma unroll
        for (int r = 0; r < 4; ++r) v[r] = f2bf(acc[ot][ct][r] * scale);
        int o = wid * 16 * OT + ot * 16 + 4 * g;
        *(us4*)(outB + ((size_t)b * NPIX + p) * OC + o) = v;
      } else {
#pragma unroll
        for (int r = 0; r < 4; ++r) {
          int o = wid * 16 * OT + ot * 16 + 4 * g + r;
          size_t oi = ((size_t)b * OC + o) * NPIX + p;
          float v = acc[ot][ct][r];
          if constexpr (RES) v += res[oi];
          outF[oi] = v;
        }
      }
    }
}

// ---------------- K2: depthwise 3x3 for k and v (channel-split) ---------------
__global__ __launch_bounds__(256) void k_dwkv(
    const float* __restrict__ xn,
    const float* __restrict__ kw, const float* __restrict__ kb,
    const float* __restrict__ vw, const float* __restrict__ vb,
    unsigned short* __restrict__ K, unsigned short* __restrict__ VT)
{
  int idx = blockIdx.x * 256 + threadIdx.x;
  int b = idx >> 12, p = idx & 4095;
  int h = p >> 6, w = p & 63;
  int c0 = blockIdx.y * 8;
  size_t base = (size_t)b * CH * NPIX;
  unsigned short kq[8];
#pragma unroll
  for (int j = 0; j < 8; ++j) {
    int c = c0 + j;
    const float* xc = xn + base + (size_t)c * NPIX;
    float ka = kb[c], va = vb[c];
#pragma unroll
    for (int dy = -1; dy <= 1; ++dy) {
#pragma unroll
      for (int dx = -1; dx <= 1; ++dx) {
        int hh = h + dy, ww = w + dx;
        float xvv = (hh >= 0 && hh < 64 && ww >= 0 && ww < 64) ? xc[hh * 64 + ww] : 0.f;
        int t = (dy + 1) * 3 + (dx + 1);
        ka += kw[c * 9 + t] * xvv;
        va += vw[c * 9 + t] * xvv;
      }
    }
    kq[j] = f2bf(ka);
    VT[((size_t)b * CH + c) * NPIX + p] = f2bf(va);
  }
  *(short8*)(K + (size_t)idx * 64 + c0) = *(short8*)(kq);
}

// ---------------- K3: attention, swapped-operand, barrier-free main loop ------
// Wave owns a 256-key range. S^T = mfma(K, Q^T); K rows loaded with permutation
// key = 8*(l15>>2) + 4t + (l15&3) so exp'd S^T regs ARE the k=32 PV B-frag.
// O^T = mfma(V^T, P^T). No LDS, no barriers in the loop; 18KB LDS epilogue.
__global__ __launch_bounds__(256) void k_attn(
    const unsigned short* __restrict__ Q, const unsigned short* __restrict__ K,
    const unsigned short* __restrict__ VT, float* __restrict__ OP, float* __restrict__ LS)
{
  __shared__ float red[4][16][68];             // [wave][qrow16][ch64+pad]
  __shared__ float lsls[4][4][16];             // [wave][qt][qrow16]

  int tid = threadIdx.x;
  int wid = tid >> 6, lane = tid & 63;
  int l15 = lane & 15, g = lane >> 4;
  int b = blockIdx.y, split = blockIdx.z;
  int qbase = blockIdx.x * 64;

  const unsigned short* Qb = Q + (size_t)b * NPIX * CH;
  const unsigned short* Kb = K + (size_t)b * NPIX * CH;
  const unsigned short* Vb = VT + (size_t)b * CH * NPIX;

  // Q as B-frags (Q^T): qf[qt][kc] = Q[qbase+qt*16+l15][kc*32+8g..+7]
  short8 qf[4][2];
#pragma unroll
  for (int qt = 0; qt < 4; ++qt)
#pragma unroll
    for (int kc = 0; kc < 2; ++kc)
      qf[qt][kc] = *(const short8*)(Qb + (size_t)(qbase + qt * 16 + l15) * CH + kc * 32 + 8 * g);

  f32x4 acc[4][4];                             // [qt][cs] : O^T[ch=cs*16+4g+r][qrow=qt*16+l15]
#pragma unroll
  for (int qt = 0; qt < 4; ++qt)
#pragma unroll
    for (int cs = 0; cs < 4; ++cs) acc[qt][cs] = (f32x4){0.f, 0.f, 0.f, 0.f};
  float lsum[4] = {0.f, 0.f, 0.f, 0.f};

  int kperm = 8 * (l15 >> 2) + (l15 & 3);      // tile-row permutation
  int kbase = split * 1024 + wid * 256;

  for (int s = 0; s < 8; ++s) {
    int key0 = kbase + s * 32;
    // K A-frags (permuted rows), tiles t=0/1
    const unsigned short* kp = Kb + (size_t)(key0 + kperm) * CH + 8 * g;
    short8 kf00 = *(const short8*)(kp);
    short8 kf01 = *(const short8*)(kp + 32);
    short8 kf10 = *(const short8*)(kp + 4 * CH);
    short8 kf11 = *(const short8*)(kp + 4 * CH + 32);
    // V^T A-frags: vf[cs] = VT[cs*16+l15][key0+8g..+7]
    const unsigned short* vp = Vb + (size_t)l15 * NPIX + key0 + 8 * g;
    short8 vf0 = *(const short8*)(vp);
    short8 vf1 = *(const short8*)(vp + 16 * NPIX);
    short8 vf2 = *(const short8*)(vp + 32 * NPIX);
    short8 vf3 = *(const short8*)(vp + 48 * NPIX);

#pragma unroll
    for (int qt = 0; qt < 4; ++qt) {
      f32x4 s0 = {0.f, 0.f, 0.f, 0.f}, s1 = {0.f, 0.f, 0.f, 0.f};
      s0 = __builtin_amdgcn_mfma_f32_16x16x32_bf16(kf00, qf[qt][0], s0, 0, 0, 0);
      s0 = __builtin_amdgcn_mfma_f32_16x16x32_bf16(kf01, qf[qt][1], s0, 0, 0, 0);
      s1 = __builtin_amdgcn_mfma_f32_16x16x32_bf16(kf10, qf[qt][0], s1, 0, 0, 0);
      s1 = __builtin_amdgcn_mfma_f32_16x16x32_bf16(kf11, qf[qt][1], s1, 0, 0, 0);
      // P = exp(S^T) (fixed-max softmax); regs are already the PV B-frag
      float p0 = __expf(s0[0]), p1 = __expf(s0[1]), p2 = __expf(s0[2]), p3 = __expf(s0[3]);
      float p4 = __expf(s1[0]), p5 = __expf(s1[1]), p6 = __expf(s1[2]), p7 = __expf(s1[3]);
      lsum[qt] += (p0 + p1) + (p2 + p3) + (p4 + p5) + (p6 + p7);
      u32x4 pk;
      pk[0] = cvtpk(p0, p1); pk[1] = cvtpk(p2, p3);
      pk[2] = cvtpk(p4, p5); pk[3] = cvtpk(p6, p7);
      short8 pb = *(short8*)&pk;
      acc[qt][0] = __builtin_amdgcn_mfma_f32_16x16x32_bf16(vf0, pb, acc[qt][0], 0, 0, 0);
      acc[qt][1] = __builtin_amdgcn_mfma_f32_16x16x32_bf16(vf1, pb, acc[qt][1], 0, 0, 0);
      acc[qt][2] = __builtin_amdgcn_mfma_f32_16x16x32_bf16(vf2, pb, acc[qt][2], 0, 0, 0);
      acc[qt][3] = __builtin_amdgcn_mfma_f32_16x16x32_bf16(vf3, pb, acc[qt][3], 0, 0, 0);
    }
  }

  // lsum: sum over key-groups (g); result uniform across g for (qt, qrow=l15)
#pragma unroll
  for (int qt = 0; qt < 4; ++qt) {
    lsum[qt] += __shfl_xor(lsum[qt], 16, 64);
    lsum[qt] += __shfl_xor(lsum[qt], 32, 64);
  }
  if (g == 0) {
#pragma unroll
    for (int qt = 0; qt < 4; ++qt) lsls[wid][qt][l15] = lsum[qt];
  }

  size_t sb = (size_t)split * BATCH * NPIX + (size_t)b * NPIX;
#pragma unroll
  for (int qt = 0; qt < 4; ++qt) {
    __syncthreads();
#pragma unroll
    for (int cs = 0; cs < 4; ++cs)
      *(f32x4*)&red[wid][l15][cs * 16 + 4 * g] = acc[qt][cs];
    __syncthreads();
    int q = tid >> 4, ch = (tid & 15) * 4;
    f32x4 v = *(f32x4*)&red[0][q][ch];
    v += *(f32x4*)&red[1][q][ch];
    v += *(f32x4*)&red[2][q][ch];
    v += *(f32x4*)&red[3][q][ch];
    *(f32x4*)(OP + (sb + qbase + qt * 16 + q) * 64 + ch) = v;
  }
  __syncthreads();
  if (tid < 64) {
    int qt = tid >> 4, q = tid & 15;
    LS[sb + qbase + qt * 16 + q] =
        lsls[0][qt][q] + lsls[1][qt][q] + lsls[2][qt][q] + lsls[3][qt][q];
  }
}

// ------------- K_reduce: split-reduce + normalize -> AOT bf16 (B,N,64) --------
__global__ __launch_bounds__(256) void k_reduce(
    const float* __restrict__ OP, const float* __restrict__ LS,
    unsigned short* __restrict__ AOT)
{
  __shared__ float aT[64][65];
  int tid = threadIdx.x, px = tid & 63, g = tid >> 6;
  int idx0 = blockIdx.x * 64;
  int idx = idx0 + px;

  f32x4 a0 = {0.f,0.f,0.f,0.f}, a1 = {0.f,0.f,0.f,0.f};
  f32x4 a2 = {0.f,0.f,0.f,0.f}, a3 = {0.f,0.f,0.f,0.f};
  float ls = 0.f;
#pragma unroll
  for (int s = 0; s < NSPLIT; ++s) {
    const f32x4* base = (const f32x4*)(OP + ((size_t)s * BATCH * NPIX + idx0) * 64);
    a0 += base[tid];
    a1 += base[tid + 256];
    a2 += base[tid + 512];
    a3 += base[tid + 768];
    ls += LS[(size_t)s * BATCH * NPIX + idx];
  }
  float inv = 1.f / ls;
  int pxw = tid >> 4, c0 = (tid & 15) * 4;
#pragma unroll
  for (int i = 0; i < 4; ++i) {
    aT[c0 + i][pxw +  0] = a0[i];
    aT[c0 + i][pxw + 16] = a1[i];
    aT[c0 + i][pxw + 32] = a2[i];
    aT[c0 + i][pxw + 48] = a3[i];
  }
  __syncthreads();

  float av[64];
#pragma unroll
  for (int c = 0; c < 64; ++c) av[c] = aT[c][px] * inv;

  unsigned short* tp = AOT + (size_t)idx * 64;
#define RD_WR(C0)                                                              \
  {                                                                            \
    unsigned short t[16];                                                      \
    _Pragma("unroll") for (int j = 0; j < 16; ++j) t[j] = f2bf(av[C0 + j]);    \
    *(short8*)(tp + C0) = *(short8*)t;                                         \
    *(short8*)(tp + C0 + 8) = *(short8*)(t + 8);                               \
  }
  if (g == 0) RD_WR(0)
  else if (g == 1) RD_WR(16)
  else if (g == 2) RD_WR(32)
  else RD_WR(48)
#undef RD_WR
}

// ------------- K6: dw3x3 + gelu + gate -> g12T bf16 (B,N,128) -----------------
__global__ __launch_bounds__(256) void k_dwgelu(
    const float* __restrict__ t1, const float* __restrict__ t2,
    const float* __restrict__ w1, const float* __restrict__ bb1,
    const float* __restrict__ w2, const float* __restrict__ bb2,
    unsigned short* __restrict__ g12T)
{
  int idx = blockIdx.x * 256 + threadIdx.x;
  int b = idx >> 12, p = idx & 4095;
  int h = p >> 6, w = p & 63;
  int c0 = blockIdx.y * 8;
  unsigned short outv[8];
#pragma unroll
  for (int j = 0; j < 8; ++j) {
    int c = c0 + j;
    size_t tb = ((size_t)b * 128 + c) * NPIX;
    float a1 = bb1[c], a2 = bb2[c];
#pragma unroll
    for (int dy = -1; dy <= 1; ++dy) {
#pragma unroll
      for (int dx = -1; dx <= 1; ++dx) {
        int hh = h + dy, ww = w + dx;
        bool ok = (hh >= 0 && hh < 64 && ww >= 0 && ww < 64);
        float v1 = ok ? t1[tb + hh * 64 + ww] : 0.f;
        float v2 = ok ? t2[tb + hh * 64 + ww] : 0.f;
        int t = (dy + 1) * 3 + (dx + 1);
        a1 += w1[c * 9 + t] * v1;
        a2 += w2[c * 9 + t] * v2;
      }
    }
    float ge1 = 0.5f * a1 * (1.f + erff(a1 * 0.70710678118654752f));
    float ge2 = 0.5f * a2 * (1.f + erff(a2 * 0.70710678118654752f));
    outv[j] = f2bf(ge1 * ge2);
  }
  *(short8*)(g12T + (size_t)idx * 128 + c0) = *(short8*)outv;
}

extern "C" void kernel_launch(void* const* d_in, const int* in_sizes, int n_in,
                              void* d_out, int out_size, void* d_ws, size_t ws_size,
                              hipStream_t stream) {
  const float* x        = (const float*)d_in[0];
  const float* cta_ln_g = (const float*)d_in[1];
  const float* cta_ln_b = (const float*)d_in[2];
  const float* q_w      = (const float*)d_in[3];
  const float* q_b      = (const float*)d_in[4];
  const float* k_w      = (const float*)d_in[5];
  const float* k_b      = (const float*)d_in[6];
  const float* v_w      = (const float*)d_in[7];
  const float* v_b      = (const float*)d_in[8];
  const float* cta_out_w= (const float*)d_in[9];
  const float* cta_out_b= (const float*)d_in[10];
  const float* nle_ln_g = (const float*)d_in[11];
  const float* nle_ln_b = (const float*)d_in[12];
  const float* b1_w1    = (const float*)d_in[13];
  const float* b1_b1    = (const float*)d_in[14];
  const float* b1_w2    = (const float*)d_in[15];
  const float* b1_b2    = (const float*)d_in[16];
  const float* b2_w1    = (const float*)d_in[17];
  const float* b2_b1    = (const float*)d_in[18];
  const float* b2_w2    = (const float*)d_in[19];
  const float* b2_b2    = (const float*)d_in[20];
  const float* nle_out_w= (const float*)d_in[21];
  const float* nle_out_b= (const float*)d_in[22];

  char* ws = (char*)d_ws;
  float*          xn   = (float*)(ws);                         // 0..4M (reused: g12T)
  unsigned short* xnT  = (unsigned short*)(ws + (4u  << 20));  // 4..6
  unsigned short* Qb   = (unsigned short*)(ws + (6u  << 20));  // 6..8
  unsigned short* Kb   = (unsigned short*)(ws + (8u  << 20));  // 8..10
  unsigned short* VTb  = (unsigned short*)(ws + (10u << 20));  // 10..12
  float*          OP   = (float*)(ws + (12u << 20));           // 12..28 (reused: t1,t2)
  float*          LSb  = (float*)(ws + (28u << 20));           // 28..28.25
  unsigned short* AOT  = (unsigned short*)(ws + (29u << 20));  // 29..31
  float*          xatt = (float*)(ws + (31u << 20));           // 31..35
  unsigned short* xn2T = (unsigned short*)(ws + (35u << 20));  // 35..37
  float*          t1   = (float*)(ws + (12u << 20));           // 12..20
  float*          t2   = (float*)(ws + (20u << 20));           // 20..28
  unsigned short* g12T = (unsigned short*)(ws);                // 0..4 (xn dead)

  k_ln<true>  <<<256, 256, 0, stream>>>(x, cta_ln_g, cta_ln_b, xn, xnT);
  k_gemm<64, 64, false, true>  <<<dim3(64, 4), 256, 0, stream>>>(q_w, q_b, xnT, nullptr, 0.125f, nullptr, Qb);
  k_dwkv      <<<dim3(64, 8), 256, 0, stream>>>(xn, k_w, k_b, v_w, v_b, Kb, VTb);
  k_attn      <<<dim3(64, BATCH, NSPLIT), 256, 0, stream>>>(Qb, Kb, VTb, OP, LSb);
  k_reduce    <<<256, 256, 0, stream>>>(OP, LSb, AOT);
  k_gemm<64, 64, true, false>  <<<dim3(64, 4), 256, 0, stream>>>(cta_out_w, cta_out_b, AOT, x, 1.f, xatt, nullptr);
  k_ln<false> <<<256, 256, 0, stream>>>(xatt, nle_ln_g, nle_ln_b, nullptr, xn2T);
  k_gemm<128, 64, false, false><<<dim3(64, 4), 256, 0, stream>>>(b1_w1, b1_b1, xn2T, nullptr, 1.f, t1, nullptr);
  k_gemm<128, 64, false, false><<<dim3(64, 4), 256, 0, stream>>>(b2_w1, b2_b1, xn2T, nullptr, 1.f, t2, nullptr);
  k_dwgelu    <<<dim3(64, 16), 256, 0, stream>>>(t1, t2, b1_w2, b1_b2, b2_w2, b2_b2, g12T);
  k_gemm<64, 128, true, false> <<<dim3(64, 4), 256, 0, stream>>>(nle_out_w, nle_out_b, g12T, xatt, 1.f, (float*)d_out, nullptr);
}

// Round 7
// 87.482 us; speedup vs baseline: 1.1520x; 1.1520x over previous
//
#include <hip/hip_runtime.h>
#include <hip/hip_bf16.h>
#include <math.h>

#define NPIX 4096
#define CH 64
#define BATCH 4
#define NSPLIT 4

typedef __attribute__((ext_vector_type(8))) short short8;
typedef __attribute__((ext_vector_type(4))) float f32x4;
typedef __attribute__((ext_vector_type(4))) unsigned short us4;
typedef __attribute__((ext_vector_type(4))) unsigned int u32x4;

static __device__ __forceinline__ unsigned short f2bf(float f) {
  union { float f; unsigned u; } v; v.f = f;
  unsigned u = v.u;
  unsigned r = u + 0x7FFF + ((u >> 16) & 1);
  return (unsigned short)(r >> 16);
}
static __device__ __forceinline__ float bf2f(unsigned short u) {
  union { unsigned u; float f; } v; v.u = ((unsigned)u) << 16; return v.f;
}
static __device__ __forceinline__ unsigned cvtpk(float lo, float hi) {
  unsigned r;
  asm("v_cvt_pk_bf16_f32 %0, %1, %2" : "=v"(r) : "v"(lo), "v"(hi));
  return r;
}

// ---------------- K1: LayerNorm(C) + q-proj MFMA GEMM, fused ------------------
__global__ __launch_bounds__(256) void k_ln_q(
    const float* __restrict__ x, const float* __restrict__ lg, const float* __restrict__ lb,
    const float* __restrict__ qw, const float* __restrict__ qb,
    float* __restrict__ xn, unsigned short* __restrict__ Q)
{
  __shared__ float xT[64][64];                 // [c][px] f32
  __shared__ unsigned short xB[64][64];        // [px][c] bf16, chunk-swizzled
  int tid = threadIdx.x, px = tid & 63, g4 = tid >> 6;
  int idx0 = blockIdx.x * 64;
  int idx = idx0 + px;
  int b = idx >> 12, p = idx & 4095;
  const float* xb = x + (size_t)b * CH * NPIX + p;
  for (int j = 0; j < 16; ++j) { int c = 16 * g4 + j; xT[c][px] = xb[(size_t)c * NPIX]; }
  __syncthreads();
  float xv[64]; float s = 0.f;
#pragma unroll
  for (int c = 0; c < 64; ++c) { xv[c] = xT[c][px]; s += xv[c]; }
  float mu = s * (1.f / 64.f), vs = 0.f;
#pragma unroll
  for (int c = 0; c < 64; ++c) { float d = xv[c] - mu; vs += d * d; }
  float rs = rsqrtf(vs * (1.f / 64.f) + 1e-5f);
#pragma unroll
  for (int c = 0; c < 64; ++c) xv[c] = (xv[c] - mu) * rs * lg[c] + lb[c];

  float* xnb = xn + (size_t)b * CH * NPIX + p;
#define LNQ_WR(C0)                                                             \
  {                                                                            \
    unsigned short t[16];                                                      \
    _Pragma("unroll") for (int j = 0; j < 16; ++j) {                           \
      float v = xv[C0 + j];                                                    \
      xnb[(size_t)(C0 + j) * NPIX] = v;                                        \
      t[j] = f2bf(v);                                                          \
    }                                                                          \
    *(short8*)&xB[px][(((C0 / 8) + 0) ^ (px & 7)) * 8] = *(short8*)t;          \
    *(short8*)&xB[px][(((C0 / 8) + 1) ^ (px & 7)) * 8] = *(short8*)(t + 8);    \
  }
  if (g4 == 0) LNQ_WR(0)
  else if (g4 == 1) LNQ_WR(16)
  else if (g4 == 2) LNQ_WR(32)
  else LNQ_WR(48)
#undef LNQ_WR
  __syncthreads();

  // GEMM phase: q = qw * xn^T, scaled 0.125 (1/sqrt(64)), bf16 pixel-major out
  int lane = tid & 63, l15 = lane & 15, gg = lane >> 4;
  short8 af[2];
#pragma unroll
  for (int kc = 0; kc < 2; ++kc) {
    const float* wp = qw + (size_t)(g4 * 16 + l15) * 64 + kc * 32 + 8 * gg;
    unsigned short t[8];
#pragma unroll
    for (int j = 0; j < 8; ++j) t[j] = f2bf(wp[j]);
    af[kc] = *(short8*)t;
  }
  float bv[4];
#pragma unroll
  for (int r = 0; r < 4; ++r) bv[r] = qb[g4 * 16 + 4 * gg + r];
#pragma unroll
  for (int ct = 0; ct < 4; ++ct) {
    f32x4 acc = {bv[0], bv[1], bv[2], bv[3]};
    int row = ct * 16 + l15;
    short8 bf0 = *(const short8*)&xB[row][((0 + gg) ^ (row & 7)) * 8];
    short8 bf1 = *(const short8*)&xB[row][((4 + gg) ^ (row & 7)) * 8];
    acc = __builtin_amdgcn_mfma_f32_16x16x32_bf16(af[0], bf0, acc, 0, 0, 0);
    acc = __builtin_amdgcn_mfma_f32_16x16x32_bf16(af[1], bf1, acc, 0, 0, 0);
    us4 v;
#pragma unroll
    for (int r = 0; r < 4; ++r) v[r] = f2bf(acc[r] * 0.125f);
    *(us4*)(Q + (size_t)(idx0 + row) * 64 + g4 * 16 + 4 * gg) = v;
  }
}

// ---------------- K2: depthwise 3x3 for k and v (channel-split) ---------------
__global__ __launch_bounds__(256) void k_dwkv(
    const float* __restrict__ xn,
    const float* __restrict__ kw, const float* __restrict__ kb,
    const float* __restrict__ vw, const float* __restrict__ vb,
    unsigned short* __restrict__ K, unsigned short* __restrict__ VT)
{
  int idx = blockIdx.x * 256 + threadIdx.x;
  int b = idx >> 12, p = idx & 4095;
  int h = p >> 6, w = p & 63;
  int c0 = blockIdx.y * 8;
  size_t base = (size_t)b * CH * NPIX;
  unsigned short kq[8];
#pragma unroll
  for (int j = 0; j < 8; ++j) {
    int c = c0 + j;
    const float* xc = xn + base + (size_t)c * NPIX;
    float ka = kb[c], va = vb[c];
#pragma unroll
    for (int dy = -1; dy <= 1; ++dy) {
#pragma unroll
      for (int dx = -1; dx <= 1; ++dx) {
        int hh = h + dy, ww = w + dx;
        float xvv = (hh >= 0 && hh < 64 && ww >= 0 && ww < 64) ? xc[hh * 64 + ww] : 0.f;
        int t = (dy + 1) * 3 + (dx + 1);
        ka += kw[c * 9 + t] * xvv;
        va += vw[c * 9 + t] * xvv;
      }
    }
    kq[j] = f2bf(ka);
    VT[((size_t)b * CH + c) * NPIX + p] = f2bf(va);
  }
  *(short8*)(K + (size_t)idx * 64 + c0) = *(short8*)(kq);
}

// ---------------- K3: attention, swapped-operand, barrier-free main loop ------
__global__ __launch_bounds__(256) void k_attn(
    const unsigned short* __restrict__ Q, const unsigned short* __restrict__ K,
    const unsigned short* __restrict__ VT, unsigned short* __restrict__ OPb,
    float* __restrict__ LS)
{
  __shared__ float red[4][16][68];
  __shared__ float lsls[4][4][16];

  int tid = threadIdx.x;
  int wid = tid >> 6, lane = tid & 63;
  int l15 = lane & 15, g = lane >> 4;
  int b = blockIdx.y, split = blockIdx.z;
  int qbase = blockIdx.x * 64;

  const unsigned short* Qb = Q + (size_t)b * NPIX * CH;
  const unsigned short* Kb = K + (size_t)b * NPIX * CH;
  const unsigned short* Vb = VT + (size_t)b * CH * NPIX;

  short8 qf[4][2];
#pragma unroll
  for (int qt = 0; qt < 4; ++qt)
#pragma unroll
    for (int kc = 0; kc < 2; ++kc)
      qf[qt][kc] = *(const short8*)(Qb + (size_t)(qbase + qt * 16 + l15) * CH + kc * 32 + 8 * g);

  f32x4 acc[4][4];
#pragma unroll
  for (int qt = 0; qt < 4; ++qt)
#pragma unroll
    for (int cs = 0; cs < 4; ++cs) acc[qt][cs] = (f32x4){0.f, 0.f, 0.f, 0.f};
  float lsum[4] = {0.f, 0.f, 0.f, 0.f};

  int kperm = 8 * (l15 >> 2) + (l15 & 3);
  int kbase = split * 1024 + wid * 256;

  for (int s = 0; s < 8; ++s) {
    int key0 = kbase + s * 32;
    const unsigned short* kp = Kb + (size_t)(key0 + kperm) * CH + 8 * g;
    short8 kf00 = *(const short8*)(kp);
    short8 kf01 = *(const short8*)(kp + 32);
    short8 kf10 = *(const short8*)(kp + 4 * CH);
    short8 kf11 = *(const short8*)(kp + 4 * CH + 32);
    const unsigned short* vp = Vb + (size_t)l15 * NPIX + key0 + 8 * g;
    short8 vf0 = *(const short8*)(vp);
    short8 vf1 = *(const short8*)(vp + 16 * NPIX);
    short8 vf2 = *(const short8*)(vp + 32 * NPIX);
    short8 vf3 = *(const short8*)(vp + 48 * NPIX);

    __builtin_amdgcn_s_setprio(1);
#pragma unroll
    for (int qt = 0; qt < 4; ++qt) {
      f32x4 s0 = {0.f, 0.f, 0.f, 0.f}, s1 = {0.f, 0.f, 0.f, 0.f};
      s0 = __builtin_amdgcn_mfma_f32_16x16x32_bf16(kf00, qf[qt][0], s0, 0, 0, 0);
      s0 = __builtin_amdgcn_mfma_f32_16x16x32_bf16(kf01, qf[qt][1], s0, 0, 0, 0);
      s1 = __builtin_amdgcn_mfma_f32_16x16x32_bf16(kf10, qf[qt][0], s1, 0, 0, 0);
      s1 = __builtin_amdgcn_mfma_f32_16x16x32_bf16(kf11, qf[qt][1], s1, 0, 0, 0);
      float p0 = __expf(s0[0]), p1 = __expf(s0[1]), p2 = __expf(s0[2]), p3 = __expf(s0[3]);
      float p4 = __expf(s1[0]), p5 = __expf(s1[1]), p6 = __expf(s1[2]), p7 = __expf(s1[3]);
      lsum[qt] += (p0 + p1) + (p2 + p3) + (p4 + p5) + (p6 + p7);
      u32x4 pk;
      pk[0] = cvtpk(p0, p1); pk[1] = cvtpk(p2, p3);
      pk[2] = cvtpk(p4, p5); pk[3] = cvtpk(p6, p7);
      short8 pb = *(short8*)&pk;
      acc[qt][0] = __builtin_amdgcn_mfma_f32_16x16x32_bf16(vf0, pb, acc[qt][0], 0, 0, 0);
      acc[qt][1] = __builtin_amdgcn_mfma_f32_16x16x32_bf16(vf1, pb, acc[qt][1], 0, 0, 0);
      acc[qt][2] = __builtin_amdgcn_mfma_f32_16x16x32_bf16(vf2, pb, acc[qt][2], 0, 0, 0);
      acc[qt][3] = __builtin_amdgcn_mfma_f32_16x16x32_bf16(vf3, pb, acc[qt][3], 0, 0, 0);
    }
    __builtin_amdgcn_s_setprio(0);
  }

#pragma unroll
  for (int qt = 0; qt < 4; ++qt) {
    lsum[qt] += __shfl_xor(lsum[qt], 16, 64);
    lsum[qt] += __shfl_xor(lsum[qt], 32, 64);
  }
  if (g == 0) {
#pragma unroll
    for (int qt = 0; qt < 4; ++qt) lsls[wid][qt][l15] = lsum[qt];
  }

  size_t sb = ((size_t)split * BATCH + b) * NPIX;
#pragma unroll
  for (int qt = 0; qt < 4; ++qt) {
    __syncthreads();
#pragma unroll
    for (int cs = 0; cs < 4; ++cs)
      *(f32x4*)&red[wid][l15][cs * 16 + 4 * g] = acc[qt][cs];
    __syncthreads();
    int q = tid >> 4, ch = (tid & 15) * 4;
    f32x4 v = *(f32x4*)&red[0][q][ch];
    v += *(f32x4*)&red[1][q][ch];
    v += *(f32x4*)&red[2][q][ch];
    v += *(f32x4*)&red[3][q][ch];
    us4 o4;
#pragma unroll
    for (int i = 0; i < 4; ++i) o4[i] = f2bf(v[i]);
    *(us4*)(OPb + (sb + qbase + qt * 16 + q) * 64 + ch) = o4;
  }
  __syncthreads();
  if (tid < 64) {
    int qt = tid >> 4, q = tid & 15;
    LS[sb + qbase + qt * 16 + q] =
        lsls[0][qt][q] + lsls[1][qt][q] + lsls[2][qt][q] + lsls[3][qt][q];
  }
}

// ------------- K4: split-reduce + normalize -> AOT bf16 (no LDS) --------------
__global__ __launch_bounds__(256) void k_reduce(
    const unsigned short* __restrict__ OPb, const float* __restrict__ LSv,
    unsigned short* __restrict__ AOT)
{
  int tid = threadIdx.x;
  size_t e0 = (size_t)blockIdx.x * 4096;
#pragma unroll
  for (int h = 0; h < 2; ++h) {
    int off = (h * 256 + tid) * 8;
    int pix = blockIdx.x * 64 + (off >> 6);
    float sv[8] = {0.f, 0.f, 0.f, 0.f, 0.f, 0.f, 0.f, 0.f};
    float ls = 0.f;
#pragma unroll
    for (int sp = 0; sp < NSPLIT; ++sp) {
      short8 a = *(const short8*)(OPb + (size_t)sp * BATCH * NPIX * 64 + e0 + off);
#pragma unroll
      for (int j = 0; j < 8; ++j) sv[j] += bf2f((unsigned short)a[j]);
      ls += LSv[(size_t)sp * BATCH * NPIX + pix];
    }
    float inv = 1.f / ls;
    unsigned short t[8];
#pragma unroll
    for (int j = 0; j < 8; ++j) t[j] = f2bf(sv[j] * inv);
    *(short8*)(AOT + e0 + off) = *(short8*)t;
  }
}

// ------------- K5: out-proj GEMM + residual + LayerNorm2, fused ---------------
__global__ __launch_bounds__(256) void k_proj_ln2(
    const unsigned short* __restrict__ AOT, const float* __restrict__ x,
    const float* __restrict__ ow, const float* __restrict__ ob,
    const float* __restrict__ lg, const float* __restrict__ lb,
    float* __restrict__ xatt, unsigned short* __restrict__ xn2T)
{
  __shared__ float sm1[4][4][16], sm2[4][4][16];
  int tid = threadIdx.x;
  int wid = tid >> 6, lane = tid & 63;
  int l15 = lane & 15, g = lane >> 4;
  int b = blockIdx.y, pxb = blockIdx.x * 64;
  const unsigned short* In = AOT + ((size_t)b * NPIX + pxb) * 64;

  short8 af[2];
#pragma unroll
  for (int kc = 0; kc < 2; ++kc) {
    const float* wp = ow + (size_t)(wid * 16 + l15) * 64 + kc * 32 + 8 * g;
    unsigned short t[8];
#pragma unroll
    for (int j = 0; j < 8; ++j) t[j] = f2bf(wp[j]);
    af[kc] = *(short8*)t;
  }
  float bv[4], lgv[4], lbv[4];
#pragma unroll
  for (int r = 0; r < 4; ++r) {
    int o = wid * 16 + 4 * g + r;
    bv[r] = ob[o]; lgv[r] = lg[o]; lbv[r] = lb[o];
  }
  f32x4 acc[4];
#pragma unroll
  for (int ct = 0; ct < 4; ++ct) acc[ct] = (f32x4){bv[0], bv[1], bv[2], bv[3]};
#pragma unroll
  for (int ct = 0; ct < 4; ++ct) {
    short8 bf0 = *(const short8*)(In + (size_t)(ct * 16 + l15) * 64 + 8 * g);
    short8 bf1 = *(const short8*)(In + (size_t)(ct * 16 + l15) * 64 + 32 + 8 * g);
    acc[ct] = __builtin_amdgcn_mfma_f32_16x16x32_bf16(af[0], bf0, acc[ct], 0, 0, 0);
    acc[ct] = __builtin_amdgcn_mfma_f32_16x16x32_bf16(af[1], bf1, acc[ct], 0, 0, 0);
  }

  float xo[4][4];
#pragma unroll
  for (int ct = 0; ct < 4; ++ct) {
    int p = pxb + ct * 16 + l15;
    float s1 = 0.f, s2 = 0.f;
#pragma unroll
    for (int r = 0; r < 4; ++r) {
      int o = wid * 16 + 4 * g + r;
      size_t oi = ((size_t)b * CH + o) * NPIX + p;
      float v = acc[ct][r] + x[oi];
      xatt[oi] = v;
      xo[ct][r] = v;
      s1 += v; s2 += v * v;
    }
    s1 += __shfl_xor(s1, 16, 64); s1 += __shfl_xor(s1, 32, 64);
    s2 += __shfl_xor(s2, 16, 64); s2 += __shfl_xor(s2, 32, 64);
    if (g == 0) { sm1[wid][ct][l15] = s1; sm2[wid][ct][l15] = s2; }
  }
  __syncthreads();
#pragma unroll
  for (int ct = 0; ct < 4; ++ct) {
    int p = pxb + ct * 16 + l15;
    float mu = (sm1[0][ct][l15] + sm1[1][ct][l15] + sm1[2][ct][l15] + sm1[3][ct][l15]) * (1.f / 64.f);
    float ms = (sm2[0][ct][l15] + sm2[1][ct][l15] + sm2[2][ct][l15] + sm2[3][ct][l15]) * (1.f / 64.f);
    float rs = rsqrtf(ms - mu * mu + 1e-5f);
    us4 v4;
#pragma unroll
    for (int r = 0; r < 4; ++r) v4[r] = f2bf((xo[ct][r] - mu) * rs * lgv[r] + lbv[r]);
    *(us4*)(xn2T + ((size_t)b * NPIX + p) * 64 + wid * 16 + 4 * g) = v4;
  }
}

// ------------- K6: both branch 1x1 convs in one kernel (shared B reads) -------
__global__ __launch_bounds__(256) void k_pw_both(
    const unsigned short* __restrict__ xn2T,
    const float* __restrict__ w1, const float* __restrict__ bb1,
    const float* __restrict__ w2, const float* __restrict__ bb2,
    float* __restrict__ t1, float* __restrict__ t2)
{
  int tid = threadIdx.x;
  int wid = tid >> 6, lane = tid & 63;
  int l15 = lane & 15, g = lane >> 4;
  int b = blockIdx.y, pxb = blockIdx.x * 64;
  const unsigned short* In = xn2T + ((size_t)b * NPIX + pxb) * 64;
  const float* W  = (wid & 2) ? w2 : w1;
  const float* bb = (wid & 2) ? bb2 : bb1;
  float* t        = (wid & 2) ? t2 : t1;
  int oh = (wid & 1) * 64;

  short8 af[4][2];
#pragma unroll
  for (int ot = 0; ot < 4; ++ot)
#pragma unroll
    for (int kc = 0; kc < 2; ++kc) {
      const float* wp = W + (size_t)(oh + ot * 16 + l15) * 64 + kc * 32 + 8 * g;
      unsigned short tt[8];
#pragma unroll
      for (int j = 0; j < 8; ++j) tt[j] = f2bf(wp[j]);
      af[ot][kc] = *(short8*)tt;
    }
  f32x4 acc[4][4];
#pragma unroll
  for (int ot = 0; ot < 4; ++ot) {
    float b0 = bb[oh + ot * 16 + 4 * g + 0];
    float b1 = bb[oh + ot * 16 + 4 * g + 1];
    float b2 = bb[oh + ot * 16 + 4 * g + 2];
    float b3 = bb[oh + ot * 16 + 4 * g + 3];
#pragma unroll
    for (int ct = 0; ct < 4; ++ct) acc[ot][ct] = (f32x4){b0, b1, b2, b3};
  }
#pragma unroll
  for (int ct = 0; ct < 4; ++ct) {
    short8 bf0 = *(const short8*)(In + (size_t)(ct * 16 + l15) * 64 + 8 * g);
    short8 bf1 = *(const short8*)(In + (size_t)(ct * 16 + l15) * 64 + 32 + 8 * g);
#pragma unroll
    for (int ot = 0; ot < 4; ++ot) {
      acc[ot][ct] = __builtin_amdgcn_mfma_f32_16x16x32_bf16(af[ot][0], bf0, acc[ot][ct], 0, 0, 0);
      acc[ot][ct] = __builtin_amdgcn_mfma_f32_16x16x32_bf16(af[ot][1], bf1, acc[ot][ct], 0, 0, 0);
    }
  }
#pragma unroll
  for (int ot = 0; ot < 4; ++ot)
#pragma unroll
    for (int ct = 0; ct < 4; ++ct) {
      int p = pxb + ct * 16 + l15;
#pragma unroll
      for (int r = 0; r < 4; ++r) {
        int o = oh + ot * 16 + 4 * g + r;
        t[((size_t)b * 128 + o) * NPIX + p] = acc[ot][ct][r];
      }
    }
}

// ------------- K7: dw3x3 + gelu + gate -> g12T bf16 (B,N,128) -----------------
__global__ __launch_bounds__(256) void k_dwgelu(
    const float* __restrict__ t1, const float* __restrict__ t2,
    const float* __restrict__ w1, const float* __restrict__ bb1,
    const float* __restrict__ w2, const float* __restrict__ bb2,
    unsigned short* __restrict__ g12T)
{
  int idx = blockIdx.x * 256 + threadIdx.x;
  int b = idx >> 12, p = idx & 4095;
  int h = p >> 6, w = p & 63;
  int c0 = blockIdx.y * 8;
  unsigned short outv[8];
#pragma unroll
  for (int j = 0; j < 8; ++j) {
    int c = c0 + j;
    size_t tb = ((size_t)b * 128 + c) * NPIX;
    float a1 = bb1[c], a2 = bb2[c];
#pragma unroll
    for (int dy = -1; dy <= 1; ++dy) {
#pragma unroll
      for (int dx = -1; dx <= 1; ++dx) {
        int hh = h + dy, ww = w + dx;
        bool ok = (hh >= 0 && hh < 64 && ww >= 0 && ww < 64);
        float v1 = ok ? t1[tb + hh * 64 + ww] : 0.f;
        float v2 = ok ? t2[tb + hh * 64 + ww] : 0.f;
        int t = (dy + 1) * 3 + (dx + 1);
        a1 += w1[c * 9 + t] * v1;
        a2 += w2[c * 9 + t] * v2;
      }
    }
    float ge1 = 0.5f * a1 * (1.f + erff(a1 * 0.70710678118654752f));
    float ge2 = 0.5f * a2 * (1.f + erff(a2 * 0.70710678118654752f));
    outv[j] = f2bf(ge1 * ge2);
  }
  *(short8*)(g12T + (size_t)idx * 128 + c0) = *(short8*)outv;
}

// ------------- K8: final 1x1 (64x128) GEMM + residual -------------------------
__global__ __launch_bounds__(256) void k_out(
    const float* __restrict__ W, const float* __restrict__ bias,
    const unsigned short* __restrict__ InT, const float* __restrict__ res,
    float* __restrict__ outF)
{
  int tid = threadIdx.x;
  int wid = tid >> 6, lane = tid & 63;
  int l15 = lane & 15, g = lane >> 4;
  int b = blockIdx.y, pxb = blockIdx.x * 64;
  const unsigned short* In = InT + ((size_t)b * NPIX + pxb) * 128;

  short8 af[4];
#pragma unroll
  for (int kc = 0; kc < 4; ++kc) {
    const float* wp = W + (size_t)(wid * 16 + l15) * 128 + kc * 32 + 8 * g;
    unsigned short t[8];
#pragma unroll
    for (int j = 0; j < 8; ++j) t[j] = f2bf(wp[j]);
    af[kc] = *(short8*)t;
  }
  float bv[4];
#pragma unroll
  for (int r = 0; r < 4; ++r) bv[r] = bias[wid * 16 + 4 * g + r];
#pragma unroll
  for (int ct = 0; ct < 4; ++ct) {
    f32x4 acc = {bv[0], bv[1], bv[2], bv[3]};
#pragma unroll
    for (int kc = 0; kc < 4; ++kc) {
      short8 bf = *(const short8*)(In + (size_t)(ct * 16 + l15) * 128 + kc * 32 + 8 * g);
      acc = __builtin_amdgcn_mfma_f32_16x16x32_bf16(af[kc], bf, acc, 0, 0, 0);
    }
    int p = pxb + ct * 16 + l15;
#pragma unroll
    for (int r = 0; r < 4; ++r) {
      int o = wid * 16 + 4 * g + r;
      size_t oi = ((size_t)b * CH + o) * NPIX + p;
      outF[oi] = acc[r] + res[oi];
    }
  }
}

extern "C" void kernel_launch(void* const* d_in, const int* in_sizes, int n_in,
                              void* d_out, int out_size, void* d_ws, size_t ws_size,
                              hipStream_t stream) {
  const float* x        = (const float*)d_in[0];
  const float* cta_ln_g = (const float*)d_in[1];
  const float* cta_ln_b = (const float*)d_in[2];
  const float* q_w      = (const float*)d_in[3];
  const float* q_b      = (const float*)d_in[4];
  const float* k_w      = (const float*)d_in[5];
  const float* k_b      = (const float*)d_in[6];
  const float* v_w      = (const float*)d_in[7];
  const float* v_b      = (const float*)d_in[8];
  const float* cta_out_w= (const float*)d_in[9];
  const float* cta_out_b= (const float*)d_in[10];
  const float* nle_ln_g = (const float*)d_in[11];
  const float* nle_ln_b = (const float*)d_in[12];
  const float* b1_w1    = (const float*)d_in[13];
  const float* b1_b1    = (const float*)d_in[14];
  const float* b1_w2    = (const float*)d_in[15];
  const float* b1_b2    = (const float*)d_in[16];
  const float* b2_w1    = (const float*)d_in[17];
  const float* b2_b1    = (const float*)d_in[18];
  const float* b2_w2    = (const float*)d_in[19];
  const float* b2_b2    = (const float*)d_in[20];
  const float* nle_out_w= (const float*)d_in[21];
  const float* nle_out_b= (const float*)d_in[22];

  char* ws = (char*)d_ws;
  float*          xn   = (float*)(ws);                         // 0..4MB (reused: g12T)
  unsigned short* Qb   = (unsigned short*)(ws + (4u  << 20));  // 4..6
  unsigned short* Kb   = (unsigned short*)(ws + (6u  << 20));  // 6..8
  unsigned short* VTb  = (unsigned short*)(ws + (8u  << 20));  // 8..10
  unsigned short* OPb  = (unsigned short*)(ws + (10u << 20));  // 10..18 (4 x 2MB)
  float*          LSb  = (float*)(ws + (18u << 20));           // 18..18.25
  unsigned short* AOT  = (unsigned short*)(ws + (19u << 20));  // 19..21
  float*          xatt = (float*)(ws + (21u << 20));           // 21..25
  unsigned short* xn2T = (unsigned short*)(ws + (25u << 20));  // 25..27
  float*          t1   = (float*)(ws + (27u << 20));           // 27..35
  float*          t2   = (float*)(ws + (35u << 20));           // 35..43
  unsigned short* g12T = (unsigned short*)(ws);                // 0..4 (xn dead)

  k_ln_q     <<<256, 256, 0, stream>>>(x, cta_ln_g, cta_ln_b, q_w, q_b, xn, Qb);
  k_dwkv     <<<dim3(64, 8), 256, 0, stream>>>(xn, k_w, k_b, v_w, v_b, Kb, VTb);
  k_attn     <<<dim3(64, BATCH, NSPLIT), 256, 0, stream>>>(Qb, Kb, VTb, OPb, LSb);
  k_reduce   <<<256, 256, 0, stream>>>(OPb, LSb, AOT);
  k_proj_ln2 <<<dim3(64, 4), 256, 0, stream>>>(AOT, x, cta_out_w, cta_out_b, nle_ln_g, nle_ln_b, xatt, xn2T);
  k_pw_both  <<<dim3(64, 4), 256, 0, stream>>>(xn2T, b1_w1, b1_b1, b2_w1, b2_b1, t1, t2);
  k_dwgelu   <<<dim3(64, 16), 256, 0, stream>>>(t1, t2, b1_w2, b1_b2, b2_w2, b2_b2, g12T);
  k_out      <<<dim3(64, 4), 256, 0, stream>>>(nle_out_w, nle_out_b, g12T, xatt, (float*)d_out);
}